// Round 4
// baseline (30.461 us; speedup 1.0000x reference)
//
#include <hip/hip_runtime.h>

#define B_TOT 1024
#define SEQ 64
#define IND 32
#define HID 8
#define BPB 8   // batches per block
#define INV2PI 0.15915494309189535f

typedef __attribute__((ext_vector_type(2))) float f2;

// DPP helper (VALU-rate cross-lane)
template<int CTRL>
__device__ __forceinline__ float dppf(float v) {
    return __int_as_float(__builtin_amdgcn_update_dpp(
        0, __float_as_int(v), CTRL, 0xF, 0xF, true));
}
template<int CTRL>
__device__ __forceinline__ f2 dpp2(f2 v) {
    f2 r; r.x = dppf<CTRL>(v.x); r.y = dppf<CTRL>(v.y); return r;
}

__global__ __launch_bounds__(512, 1) void qlstm_kernel(
    const float* __restrict__ xin,
    const float* __restrict__ Wf, const float* __restrict__ bf, const float* __restrict__ thf,
    const float* __restrict__ Wi, const float* __restrict__ bi, const float* __restrict__ thi,
    const float* __restrict__ Wu, const float* __restrict__ bu, const float* __restrict__ thu,
    const float* __restrict__ Wo, const float* __restrict__ bo, const float* __restrict__ tho,
    float* __restrict__ out)
{
    // z[b][t]: 8 rows x 4 gates (f,u,i,o), pre-scaled by 1/2pi.
    // float4 slot for row r stored at quad index (r+t)&7 (t-rotation kills
    // bank conflicts on both pass-1 writes and pass-2 reads). 64 KB exactly.
    __shared__ float zs[BPB * SEQ * 32];

    const int tid = threadIdx.x;

    // ---------------- pass 1: z = (W.x + b + theta)/2pi (fully parallel) ----------------
    {
        const int b = tid >> 6;          // batch within block
        const int t = tid & 63;
        const int gb = blockIdx.x * BPB + b;
        const float4* xp = (const float4*)(xin + ((size_t)gb * SEQ + t) * IND);
        float4 x4[8];
        #pragma unroll
        for (int k = 0; k < 8; ++k) x4[k] = xp[k];

        const float* Ws[4] = {Wf, Wu, Wi, Wo};
        const float* Bs[4] = {bf, bu, bi, bo};
        const float* Ts[4] = {thf, thu, thi, tho};
        float zv[32];
        #pragma unroll
        for (int g = 0; g < 4; ++g) {
            #pragma unroll
            for (int row = 0; row < 8; ++row) {
                const float4* wr = (const float4*)(Ws[g] + row * 40);
                float a0 = Bs[g][row] + Ts[g][row], a1 = 0.f, a2 = 0.f, a3 = 0.f;
                #pragma unroll
                for (int k = 0; k < 8; ++k) {
                    float4 w4 = wr[k];
                    a0 = fmaf(w4.x, x4[k].x, a0);
                    a1 = fmaf(w4.y, x4[k].y, a1);
                    a2 = fmaf(w4.z, x4[k].z, a2);
                    a3 = fmaf(w4.w, x4[k].w, a3);
                }
                zv[row * 4 + g] = ((a0 + a1) + (a2 + a3)) * INV2PI;
            }
        }
        float4* zrow = (float4*)(zs + (b * SEQ + t) * 32);
        const float4* zvp = (const float4*)zv;
        #pragma unroll
        for (int r4 = 0; r4 < 8; ++r4) zrow[(r4 + t) & 7] = zvp[r4];
    }

    __syncthreads();
    if (tid >= 64) return;   // pass 2: wave 0 only (8 batches x 8 lanes)

    // ---------------- pass 2: serial recurrence, min-depth chain, DPP-only cross-lane ----------------
    const int l = tid;
    const int b = l >> 3;            // batch within block
    const int r = l & 7;             // row / wire
    const int gb = blockIdx.x * BPB + b;
    const bool r0  = (r == 0);
    const bool ge1 = (r >= 1), ge2 = (r >= 2), ge4 = (r >= 4);
    const f2 one2 = {1.0f, 1.0f};

    // h-dot weights, pre-permuted to DPP all-gather order hv[k] = h[r ^ m[k]],
    // pre-scaled by 1/2pi. ch0 = (f, u), ch1 = (i, o).
    const int m[8] = {0, 1, 2, 3, 7, 6, 5, 4};
    f2 wh0[8], wh1[8];
    #pragma unroll
    for (int k = 0; k < 8; ++k) {
        const int j = r * 40 + 32 + (r ^ m[k]);
        wh0[k] = (f2){Wf[j] * INV2PI, Wu[j] * INV2PI};
        wh1[k] = (f2){Wi[j] * INV2PI, Wo[j] * INV2PI};
    }

    float* obase = out + (size_t)gb * (SEQ * HID);
    const float4* zp = (const float4*)zs;
    const int zb = b * SEQ;

    float cx = 0.f, h = 0.f;
    float hv[8] = {0.f, 0.f, 0.f, 0.f, 0.f, 0.f, 0.f, 0.f};
    float4 zc = zp[(zb + 0) * 8 + (r & 7)];
    float4 z1 = zp[(zb + 1) * 8 + ((r + 1) & 7)];

    #pragma unroll 4
    for (int t = 0; t < SEQ; ++t) {
        // prefetch z two steps ahead: LDS latency never on the chain
        const int tt = (t + 2) & 63;
        float4 z2 = zp[(zb + tt) * 8 + ((r + tt) & 7)];

        // y = z + Wh.h  (4 gates packed in 2 f2 channels, 2 accumulators each)
        f2 y0a = (f2){zc.x, zc.y}, y0b = (f2){0.f, 0.f};
        f2 y1a = (f2){zc.z, zc.w}, y1b = (f2){0.f, 0.f};
        #pragma unroll
        for (int k = 0; k < 4; ++k) {
            f2 e0 = (f2){hv[2 * k],     hv[2 * k]};
            f2 e1 = (f2){hv[2 * k + 1], hv[2 * k + 1]};
            y0a += wh0[2 * k] * e0;  y0b += wh0[2 * k + 1] * e1;
            y1a += wh1[2 * k] * e0;  y1b += wh1[2 * k + 1] * e1;
        }
        f2 y0 = y0a + y0b, y1 = y1a + y1b;

        // per-wire PauliZ expectation: cos (input already in revolutions; no fract,
        // v_cos_f32 valid over +-256 rev and |y| << that)
        f2 c0, c1;
        c0.x = __builtin_amdgcn_cosf(y0.x); c0.y = __builtin_amdgcn_cosf(y0.y);
        c1.x = __builtin_amdgcn_cosf(y1.x); c1.y = __builtin_amdgcn_cosf(y1.y);

        // wire-0: all-reduce product of (r==0 ? 1 : c) over the 8-lane group
        f2 m0 = r0 ? one2 : c0, m1 = r0 ? one2 : c1;
        m0 *= dpp2<0xB1>(m0);  m1 *= dpp2<0xB1>(m1);
        m0 *= dpp2<0x4E>(m0);  m1 *= dpp2<0x4E>(m1);
        m0 *= dpp2<0x141>(m0); m1 *= dpp2<0x141>(m1);
        // wires 1..7: inclusive prefix product
        f2 v0 = c0, v1 = c1, tt0, tt1;
        tt0 = dpp2<0x111>(v0); tt1 = dpp2<0x111>(v1);
        v0 *= ge1 ? tt0 : one2;  v1 *= ge1 ? tt1 : one2;
        tt0 = dpp2<0x112>(v0); tt1 = dpp2<0x112>(v1);
        v0 *= ge2 ? tt0 : one2;  v1 *= ge2 ? tt1 : one2;
        tt0 = dpp2<0x114>(v0); tt1 = dpp2<0x114>(v1);
        v0 *= ge4 ? tt0 : one2;  v1 *= ge4 ? tt1 : one2;
        f2 q0 = r0 ? m0 : v0, q1 = r0 ? m1 : v1;

        // activations: f,i,o sigmoid (raw rcp), u tanh
        float ef = __expf(-q0.x);
        float eg = __expf(q0.y + q0.y);
        float ei = __expf(-q1.x);
        float eo = __expf(-q1.y);
        float f_ = __builtin_amdgcn_rcpf(1.0f + ef);
        float g_ = fmaf(-2.0f, __builtin_amdgcn_rcpf(1.0f + eg), 1.0f);
        float i_ = __builtin_amdgcn_rcpf(1.0f + ei);
        float o_ = __builtin_amdgcn_rcpf(1.0f + eo);

        // cell
        cx = fmaf(f_, cx, i_ * g_);
        float e2 = __expf(cx + cx);
        float th = fmaf(-2.0f, __builtin_amdgcn_rcpf(1.0f + e2), 1.0f);
        h = o_ * th;

        obase[t * HID + r] = h;   // divergence-free, off-chain

        // h all-gather: hv[k] = h[r ^ m[k]]
        hv[0] = h;
        hv[1] = dppf<0xB1>(h);
        hv[2] = dppf<0x4E>(hv[0]);
        hv[3] = dppf<0x4E>(hv[1]);
        hv[4] = dppf<0x141>(hv[0]);
        hv[5] = dppf<0x141>(hv[1]);
        hv[6] = dppf<0x141>(hv[2]);
        hv[7] = dppf<0x141>(hv[3]);

        zc = z1; z1 = z2;
    }

    const size_t hxoff = (size_t)B_TOT * SEQ * HID;
    out[hxoff + (size_t)gb * HID + r] = h;
    out[hxoff + (size_t)B_TOT * HID + (size_t)gb * HID + r] = cx;
}

extern "C" void kernel_launch(void* const* d_in, const int* in_sizes, int n_in,
                              void* d_out, int out_size, void* d_ws, size_t ws_size,
                              hipStream_t stream) {
    qlstm_kernel<<<128, 512, 0, stream>>>(
        (const float*)d_in[0],
        (const float*)d_in[1],  (const float*)d_in[2],  (const float*)d_in[3],
        (const float*)d_in[4],  (const float*)d_in[5],  (const float*)d_in[6],
        (const float*)d_in[7],  (const float*)d_in[8],  (const float*)d_in[9],
        (const float*)d_in[10], (const float*)d_in[11], (const float*)d_in[12],
        (float*)d_out);
}

// Round 5
// 29.235 us; speedup vs baseline: 1.0419x; 1.0419x over previous
//
#include <hip/hip_runtime.h>

#define B_TOT 1024
#define SEQ 64
#define IND 32
#define HID 8
#define BPB 4
#define ZSTRIDE 34
#define INV2PI 0.15915494309189535f

typedef __attribute__((ext_vector_type(2))) float f2;

// full-permutation DPP (all source lanes valid)
template<int CTRL>
__device__ __forceinline__ float dppx(float v) {
    return __int_as_float(__builtin_amdgcn_update_dpp(
        0, __float_as_int(v), CTRL, 0xF, 0xF, true));
}
template<int CTRL>
__device__ __forceinline__ f2 dppx2(f2 v) {
    f2 r; r.x = dppx<CTRL>(v.x); r.y = dppx<CTRL>(v.y); return r;
}
// shift DPP: invalid source lanes receive 1.0f (multiplicative identity)
template<int CTRL>
__device__ __forceinline__ float dppone(float v) {
    return __int_as_float(__builtin_amdgcn_update_dpp(
        0x3f800000, __float_as_int(v), CTRL, 0xF, 0xF, false));
}
template<int CTRL>
__device__ __forceinline__ f2 dppone2(f2 v) {
    f2 r; r.x = dppone<CTRL>(v.x); r.y = dppone<CTRL>(v.y); return r;
}

__global__ __launch_bounds__(512, 1) void qlstm_kernel(
    const float* __restrict__ xin,
    const float* __restrict__ Wf, const float* __restrict__ bf, const float* __restrict__ thf,
    const float* __restrict__ Wi, const float* __restrict__ bi, const float* __restrict__ thi,
    const float* __restrict__ Wu, const float* __restrict__ bu, const float* __restrict__ thu,
    const float* __restrict__ Wo, const float* __restrict__ bo, const float* __restrict__ tho,
    float* __restrict__ out)
{
    // z[(b*65+t)*34 + row*4 + {f,u,i,o}], pre-scaled by 1/2pi.
    // b-coefficient 65*34 % 32 = 2 and t-coefficient 34 % 32 = 2 -> ~4-way worst case.
    __shared__ float zs[BPB * 65 * ZSTRIDE];

    const int tid = threadIdx.x;

    // ---------------- pass 1: z = (W.x + b + theta)/2pi (fully parallel) ----------------
    {
        const int sub = tid >> 8;        // 0: gates {f,i}, 1: gates {u,o}
        const int idx = tid & 255;
        const int bl  = idx >> 6;        // batch within block
        const int t   = idx & 63;
        const int gb  = blockIdx.x * BPB + bl;
        const float4* xp = (const float4*)(xin + ((size_t)gb * SEQ + t) * IND);
        float4 x4[8];
        #pragma unroll
        for (int k = 0; k < 8; ++k) x4[k] = xp[k];

        float* zrow = zs + (bl * 65 + t) * ZSTRIDE;
        #pragma unroll
        for (int j = 0; j < 16; ++j) {
            const int row  = j & 7;
            const int gidx = ((j >> 3) << 1) | sub;   // f=0,u=1,i=2,o=3
            const float* W = sub ? (j < 8 ? Wu : Wo) : (j < 8 ? Wf : Wi);
            const float* B = sub ? (j < 8 ? bu : bo) : (j < 8 ? bf : bi);
            const float* T = sub ? (j < 8 ? thu : tho) : (j < 8 ? thf : thi);
            const float4* wr = (const float4*)(W + row * 40);
            float a0 = B[row] + T[row], a1 = 0.f, a2 = 0.f, a3 = 0.f;
            #pragma unroll
            for (int k = 0; k < 8; ++k) {
                float4 w4 = wr[k];
                a0 = fmaf(w4.x, x4[k].x, a0);
                a1 = fmaf(w4.y, x4[k].y, a1);
                a2 = fmaf(w4.z, x4[k].z, a2);
                a3 = fmaf(w4.w, x4[k].w, a3);
            }
            zrow[row * 4 + gidx] = ((a0 + a1) + (a2 + a3)) * INV2PI;
        }
    }

    __syncthreads();
    if (tid >= 64) return;   // pass 2: wave 0, 4 batches x 16 lanes

    // ---------------- pass 2: serial recurrence, packed f2, poly activations ----------------
    const int l  = tid;
    const int b  = l >> 4;           // batch within block
    const int r  = (l >> 1) & 7;     // wire / hidden row
    const int c  = l & 1;            // channel pack: 0=(f,u), 1=(i,o)
    const int gb = blockIdx.x * BPB + b;
    const bool r0 = (r == 0);
    const bool cb = (c == 1);

    // h-dot weights: wh[k] pairs with hv[k] = h[r ^ k]; pre-scaled by 1/2pi
    const float* WX = c ? Wi : Wf;
    const float* WY = c ? Wo : Wu;
    f2 wh[8];
    #pragma unroll
    for (int k = 0; k < 8; ++k) {
        const int j = r * 40 + 32 + (r ^ k);
        wh[k] = (f2){WX[j] * INV2PI, WY[j] * INV2PI};
    }

    float* obase = out + (size_t)gb * (SEQ * HID) + r;
    const float* zbase = zs + (b * 65) * ZSTRIDE + r * 4 + c * 2;

    float cx = 0.f, h = 0.f;
    float hv0 = 0.f, hv1 = 0.f, hv2 = 0.f, hv3 = 0.f,
          hv4 = 0.f, hv5 = 0.f, hv6 = 0.f, hv7 = 0.f;
    f2 zc = *(const f2*)(zbase);
    f2 z1 = *(const f2*)(zbase + ZSTRIDE);

    const f2 P5 = { 0.00208333333f,  0.00208333333f};   // 1/480
    const f2 P3 = {-0.0208333333f,  -0.0208333333f};    // -1/48
    const f2 P1 = { 0.25f, 0.25f};
    const f2 PH = { 0.5f,  0.5f};
    const f2 one2 = {1.0f, 1.0f};

    #pragma unroll 2
    for (int t = 0; t < SEQ; ++t) {
        // prefetch z two steps ahead (never on the chain)
        f2 z2 = *(const f2*)(zbase + ((t + 2) & 63) * ZSTRIDE);

        // y = z + Wh.h  (packed, 2 accumulators; late-arriving hv3/hv7 last)
        f2 y0 = zc, y1;
        y0 += wh[0] * (f2){hv0, hv0};
        y1  = wh[4] * (f2){hv4, hv4};
        y0 += wh[1] * (f2){hv1, hv1};
        y1 += wh[5] * (f2){hv5, hv5};
        y0 += wh[2] * (f2){hv2, hv2};
        y1 += wh[6] * (f2){hv6, hv6};
        y0 += wh[3] * (f2){hv3, hv3};
        y1 += wh[7] * (f2){hv7, hv7};
        f2 y = y0 + y1;

        // per-wire PauliZ expectation (y already in revolutions)
        f2 cc;
        cc.x = __builtin_amdgcn_cosf(y.x);
        cc.y = __builtin_amdgcn_cosf(y.y);

        // wires 1..7: inclusive prefix product; row boundary == batch boundary,
        // so shr with old=1.0 needs no masks
        f2 v = cc;
        v *= dppone2<0x112>(v);   // row_shr:2  (1 wire)
        v *= dppone2<0x114>(v);   // row_shr:4  (2 wires)
        v *= dppone2<0x118>(v);   // row_shr:8  (4 wires)
        // wire 0: all-reduce product of (r==0 ? 1 : c) via parity-preserving rotations
        f2 mm = { r0 ? 1.0f : cc.x, r0 ? 1.0f : cc.y };
        mm *= dppx2<0x122>(mm);   // row_ror:2
        mm *= dppx2<0x124>(mm);   // row_ror:4
        mm *= dppx2<0x128>(mm);   // row_ror:8
        f2 q = { r0 ? mm.x : v.x, r0 ? mm.y : v.y };

        // activations, |q| <= 1 (product of cosines):
        // sigmoid: deg-5 poly; tanh (u gate): Pade[5/4]
        f2 s  = q * q;
        f2 p  = s * P5 + P3;
        p     = s * p + P1;
        f2 sg = q * p + PH;
        float sy  = s.y;
        float n54 = fmaf(sy + 105.0f, sy, 945.0f);
        float d54 = fmaf(fmaf(15.0f, sy, 420.0f), sy, 945.0f);
        float t54 = q.y * n54 * __builtin_amdgcn_rcpf(d54);
        float ax = sg.x;                 // f (c0) | i (c1): sigmoid
        float ay = cb ? sg.y : t54;      // o (c1): sigmoid | u (c0): tanh

        // exchange with partner lane (^1): each lane assembles all 4 gates
        float bx = dppx<0xB1>(ax);
        float by = dppx<0xB1>(ay);
        float f_ = cb ? bx : ax;
        float i_ = cb ? ax : bx;
        float g_ = cb ? by : ay;
        float o_ = cb ? ay : by;

        // cell; |cx| < 2.1 -> tanh via Pade[7/6] (err ~2e-5, no exp)
        cx = fmaf(f_, cx, i_ * g_);
        float sc  = cx * cx;
        float n76 = fmaf(fmaf(sc + 378.0f, sc, 17325.0f), sc, 135135.0f);
        float d76 = fmaf(fmaf(fmaf(28.0f, sc, 3150.0f), sc, 62370.0f), sc, 135135.0f);
        float th  = cx * n76 * __builtin_amdgcn_rcpf(d76);
        h = o_ * th;

        obase[t * HID] = h;   // lane pairs write identical value to same dword

        // h all-gather: hv_k = h[wire r ^ k] (lane-XOR 2k, parity-preserving)
        hv0 = h;
        hv1 = dppx<0x4E>(h);            // lane^2  = wire^1
        float a7 = dppx<0x141>(h);      // lane^7  (intermediate, c-mixed)
        hv2 = dppx<0x1B>(a7);           // ^3 after ^7 -> lane^4 = wire^2
        hv3 = dppx<0x4E>(hv2);          // wire^3
        hv4 = dppx<0x128>(h);           // lane^8  = wire^4
        hv5 = dppx<0x128>(hv1);         // wire^5
        hv6 = dppx<0x128>(hv2);         // wire^6
        hv7 = dppx<0x128>(hv3);         // wire^7

        zc = z1; z1 = z2;
    }

    const size_t hxoff = (size_t)B_TOT * SEQ * HID;
    out[hxoff + (size_t)gb * HID + r] = h;
    out[hxoff + (size_t)B_TOT * HID + (size_t)gb * HID + r] = cx;
}

extern "C" void kernel_launch(void* const* d_in, const int* in_sizes, int n_in,
                              void* d_out, int out_size, void* d_ws, size_t ws_size,
                              hipStream_t stream) {
    qlstm_kernel<<<256, 512, 0, stream>>>(
        (const float*)d_in[0],
        (const float*)d_in[1],  (const float*)d_in[2],  (const float*)d_in[3],
        (const float*)d_in[4],  (const float*)d_in[5],  (const float*)d_in[6],
        (const float*)d_in[7],  (const float*)d_in[8],  (const float*)d_in[9],
        (const float*)d_in[10], (const float*)d_in[11], (const float*)d_in[12],
        (float*)d_out);
}